// Round 6
// baseline (697.987 us; speedup 1.0000x reference)
//
#include <hip/hip_runtime.h>
#include <math.h>

typedef _Float16 half_t;
typedef __attribute__((ext_vector_type(8))) _Float16 half8;
typedef __attribute__((ext_vector_type(16))) float floatx16;

__device__ __forceinline__ float gelu_exact(float v) {
    return 0.5f * v * (1.0f + erff(v * 0.7071067811865476f));
}

__device__ __forceinline__ floatx16 zero16() {
    floatx16 z;
#pragma unroll
    for (int i = 0; i < 16; ++i) z[i] = 0.f;
    return z;
}

// XOR swizzle on 16B-chunk index: spreads staging writes across all banks,
// keeps reads a per-half-wave lane permutation (conflict-free both ways).
__device__ __forceinline__ int sw_ci(int ci) {
    return ci ^ (((ci >> 5) ^ (ci >> 8)) & 31);
}

#define MFMA16(a, b, c) __builtin_amdgcn_mfma_f32_32x32x16_f16((a), (b), (c), 0, 0, 0)

// ---------------- prep ----------------
// W [h][k][n] fp32 -> Wsw: B-fragment-swizzled f16 [h][ks][j][l][jj]
//   element (k,n): ks=k>>4, j=n>>5, l=32*((k>>3)&1)+(n&31), jj=k&7  (validated r3-r5)
// Za tables [32 n][256 k] f16: row 2h = W[h]·A[h][0:256], 2h+1 = W[h]·A[h][256:512]
__global__ __launch_bounds__(256) void prep(const float* __restrict__ W0,
                                            const float* __restrict__ A0,
                                            const float* __restrict__ W1,
                                            const float* __restrict__ A1,
                                            half_t* __restrict__ Wsw0, half_t* __restrict__ Wsw1,
                                            half_t* __restrict__ Zah0, half_t* __restrict__ Zal0,
                                            half_t* __restrict__ Zah1, half_t* __restrict__ Zal1) {
    __shared__ float tile[32][257];
    const int t  = threadIdx.x;
    const int kb = blockIdx.x & 7;
    const int h  = (blockIdx.x >> 3) & 3;
    const int tz = blockIdx.x >> 5;
    const float* W = tz ? W1 : W0;
    const float* A = tz ? A1 : A0;
    half_t* Wsw = tz ? Wsw1 : Wsw0;
    half_t* Zh  = tz ? Zah1 : Zah0;
    half_t* Zl  = tz ? Zal1 : Zal0;

    for (int i = 0; i < 32; ++i)
        tile[i][t] = W[(size_t)(h * 256 + kb * 32 + i) * 256 + t];
    __syncthreads();

    const int j = t >> 5, lmn = t & 31;
#pragma unroll
    for (int i0 = 0; i0 < 32; i0 += 8) {
        const int ks = 2 * kb + (i0 >> 4);
        const int q  = (i0 >> 3) & 1;
        half_t hb[8];
#pragma unroll
        for (int ii = 0; ii < 8; ++ii) hb[ii] = (half_t)tile[i0 + ii][t];
        size_t off = ((size_t)(h * 16 + ks) * 8 + j) * 512 + (size_t)(32 * q + lmn) * 8;
        *(half8*)&Wsw[off] = *(half8*)hb;
    }

    if (kb == 0) {
        const float4* Wr = (const float4*)&W[(size_t)(h * 256 + t) * 256];
        const float4* Al = (const float4*)&A[h * 512];
        const float4* Ah = (const float4*)&A[h * 512 + 256];
        float wl = 0.f, wh = 0.f;
        for (int d = 0; d < 64; ++d) {
            float4 wv = Wr[d], a0 = Al[d], a1 = Ah[d];
            wl += wv.x * a0.x + wv.y * a0.y + wv.z * a0.z + wv.w * a0.w;
            wh += wv.x * a1.x + wv.y * a1.y + wv.z * a1.z + wv.w * a1.w;
        }
        half_t hi = (half_t)wl;
        Zh[(2 * h) * 256 + t] = hi;
        Zl[(2 * h) * 256 + t] = (half_t)(wl - (float)hi);
        hi = (half_t)wh;
        Zh[(2 * h + 1) * 256 + t] = hi;
        Zl[(2 * h + 1) * 256 + t] = (half_t)(wh - (float)hi);
        if (h == 0) {
            for (int c = 8; c < 32; ++c) {
                Zh[c * 256 + t] = (half_t)0.f;
                Zl[c * 256 + t] = (half_t)0.f;
            }
        }
    }
}

// ---------------- fused GAT layer ----------------
// ROWS = 16*GROUPS rows/block. Wave w handles 8 tasks (head h, col-slice j=w+4*half),
// each task: MT x 1 MFMA tile with hi/lo planes interleaved on ONE shared B-load:
// per ks: 1 global b128 (B) + 2 LDS b128 (a_hi,a_lo) -> 4 MFMAs, 4 indep chains.
// acc live = 64 regs -> no spill at __launch_bounds__(256,2).
template <int GROUPS>
__global__ __launch_bounds__(256, 2) void gat_layer(
    const float* __restrict__ x,
    const half_t* __restrict__ Wsw,
    const half_t* __restrict__ Zah, const half_t* __restrict__ Zal,
    float* __restrict__ out) {
    constexpr int ROWS = GROUPS * 16;
    constexpr int MT   = ROWS / 32;

    __shared__ half_t xsh[MT * 16 * 512];   // A-frags f16 hi  (swizzled chunks)
    __shared__ half_t xsl[MT * 16 * 512];   // A-frags f16 lo residual
    __shared__ float zlo_s[4][ROWS];
    __shared__ float zhi_s[4][ROWS];
    __shared__ float ge_s[4][ROWS];
    __shared__ float att_s[4][ROWS];

    const int t  = threadIdx.x;
    const int w  = t >> 6;
    const int l  = t & 63;
    const int lm = t & 31;
    const int q  = (t >> 5) & 1;

    // ---- stage x -> LDS A-fragment layout (swizzled, conflict-free writes) ----
    {
        const float4* xg = (const float4*)(x + (size_t)blockIdx.x * ROWS * 256);
#pragma unroll
        for (int i = 0; i < ROWS / 8; ++i) {
            int e = t + 256 * i;
            int row = e >> 5, cc = e & 31;          // k chunk of 8: k0 = 8*cc
            float4 v0 = xg[row * 64 + 2 * cc];
            float4 v1 = xg[row * 64 + 2 * cc + 1];
            half_t hb[8], lb[8];
#pragma unroll
            for (int ii = 0; ii < 8; ++ii) {
                float v = (ii < 4) ? (&v0.x)[ii] : (&v1.x)[ii - 4];
                half_t hv = (half_t)v;
                hb[ii] = hv;
                lb[ii] = (half_t)(v - (float)hv);
            }
            int m = row >> 5, r31 = row & 31, ks = cc >> 1, kq = cc & 1;
            int cs = sw_ci((m * 16 + ks) * 64 + 32 * kq + r31);
            *(half8*)&xsh[cs * 8] = *(half8*)hb;
            *(half8*)&xsl[cs * 8] = *(half8*)lb;
        }
    }
    __syncthreads();

    // ---- z-tile (wave 0 only): z = x @ (W·A), all 4 heads in cols 0..7 ----
    if (w == 0) {
        floatx16 zm[MT], zc[MT];
#pragma unroll
        for (int mt = 0; mt < MT; ++mt) { zm[mt] = zero16(); zc[mt] = zero16(); }
#pragma unroll 4
        for (int ks = 0; ks < 16; ++ks) {
            const int ko = lm * 256 + 16 * ks + 8 * q;
            half8 bh = *(const half8*)&Zah[ko];
            half8 bl = *(const half8*)&Zal[ko];
#pragma unroll
            for (int mt = 0; mt < MT; ++mt) {
                int cs = sw_ci((mt * 16 + ks) * 64 + l);
                half8 a  = *(const half8*)&xsh[cs * 8];
                half8 al = *(const half8*)&xsl[cs * 8];
                zm[mt] = MFMA16(a, bh, zm[mt]);
                zc[mt] = MFMA16(al, bh, zc[mt]);
                zc[mt] = MFMA16(a, bl, zc[mt]);
            }
        }
        if (lm < 8) {
            int h = lm >> 1;
            float* dst = (lm & 1) ? &zhi_s[h][0] : &zlo_s[h][0];
#pragma unroll
            for (int mt = 0; mt < MT; ++mt)
#pragma unroll
                for (int r = 0; r < 16; ++r) {
                    int row = 32 * mt + 4 * q + (r & 3) + 8 * (r >> 2);
                    dst[row] = zm[mt][r] + zc[mt][r];
                }
        }
    }
    __syncthreads();

    // ---- attention weights ----
    {
        int h = t >> 6, r = t & 63;
        if (r < ROWS) {
            float z = zlo_s[h][r] + zhi_s[h][r & ~15];
            ge_s[h][r] = gelu_exact(gelu_exact(z));
        }
    }
    __syncthreads();
    {
        int h = t >> 6, r = t & 63;
        if (r < ROWS) {
            int g0 = r & ~15;
            float mx = -1e30f;
#pragma unroll
            for (int i = 0; i < 16; ++i) mx = fmaxf(mx, ge_s[h][g0 + i]);
            float s = 0.f;
#pragma unroll
            for (int i = 0; i < 16; ++i) s += expf(ge_s[h][g0 + i] - mx);
            att_s[h][r] = expf(ge_s[h][r] - mx) / s;
        }
    }
    __syncthreads();

    // ---- main GEMM: 8 tasks/wave, hi/lo interleaved on shared B ----
    float outp[2][GROUPS];
#pragma unroll
    for (int hf = 0; hf < 2; ++hf)
#pragma unroll
        for (int g = 0; g < GROUPS; ++g) outp[hf][g] = 0.f;

#pragma unroll 1
    for (int h = 0; h < 4; ++h) {
#pragma unroll 1
        for (int hf = 0; hf < 2; ++hf) {
            const int jcol = w + 4 * hf;
            const half_t* Bp = Wsw + ((size_t)(h * 16) * 8 + jcol) * 512 + (size_t)l * 8;

            floatx16 ah_acc[MT], al_acc[MT];
#pragma unroll
            for (int mt = 0; mt < MT; ++mt) { ah_acc[mt] = zero16(); al_acc[mt] = zero16(); }

#pragma unroll
            for (int ks = 0; ks < 16; ++ks) {
                half8 b = *(const half8*)(Bp + (size_t)ks * 4096);
#pragma unroll
                for (int mt = 0; mt < MT; ++mt) {
                    int cs = sw_ci((mt * 16 + ks) * 64 + l);
                    half8 ah = *(const half8*)&xsh[cs * 8];
                    half8 al = *(const half8*)&xsl[cs * 8];
                    ah_acc[mt] = MFMA16(ah, b, ah_acc[mt]);
                    al_acc[mt] = MFMA16(al, b, al_acc[mt]);
                }
            }

            // fold: att-weighted row sum (planes combined in fp32), gelu, head acc
            float tp[GROUPS];
#pragma unroll
            for (int g = 0; g < GROUPS; ++g) tp[g] = 0.f;
#pragma unroll
            for (int mt = 0; mt < MT; ++mt)
#pragma unroll
                for (int k = 0; k < 4; ++k) {
                    float4 a4 = *(const float4*)&att_s[h][32 * mt + 4 * q + 8 * k];
#pragma unroll
                    for (int jj = 0; jj < 4; ++jj) {
                        int r = 4 * k + jj;
                        int row = 32 * mt + 4 * q + 8 * k + jj;
                        int g = row >> 4;
                        tp[g] = fmaf(ah_acc[mt][r] + al_acc[mt][r], (&a4.x)[jj], tp[g]);
                    }
                }
#pragma unroll
            for (int g = 0; g < GROUPS; ++g) {
                float s = tp[g] + __shfl_xor(tp[g], 32, 64);
                outp[hf][g] += gelu_exact(s);
            }
        }
    }

    // ---- store: wave w owns col-slices {w, w+4} -> cols 32w.. and 128+32w.. ----
    if (q == 0) {
#pragma unroll
        for (int g = 0; g < GROUPS; ++g) {
            size_t ro = ((size_t)blockIdx.x * GROUPS + g) * 256;
            out[ro + 32 * w + lm]        = 0.25f * outp[0][g];
            out[ro + 128 + 32 * w + lm]  = 0.25f * outp[1][g];
        }
    }
}

extern "C" void kernel_launch(void* const* d_in, const int* in_sizes, int n_in,
                              void* d_out, int out_size, void* d_ws, size_t ws_size,
                              hipStream_t stream) {
    const float* x  = (const float*)d_in[0];
    const float* W0 = (const float*)d_in[1];
    const float* A0 = (const float*)d_in[2];
    const float* W1 = (const float*)d_in[3];
    const float* A1 = (const float*)d_in[4];

    char* ws = (char*)d_ws;
    float*  y1   = (float*)ws;                  // 8 MiB: [8192][256]
    half_t* Wsw0 = (half_t*)(ws + 8388608);     // 512 KiB
    half_t* Wsw1 = (half_t*)(ws + 8912896);     // 512 KiB
    half_t* Zah0 = (half_t*)(ws + 9437184);     // 16 KiB each
    half_t* Zal0 = (half_t*)(ws + 9453568);
    half_t* Zah1 = (half_t*)(ws + 9469952);
    half_t* Zal1 = (half_t*)(ws + 9486336);

    prep<<<64, 256, 0, stream>>>(W0, A0, W1, A1, Wsw0, Wsw1, Zah0, Zal0, Zah1, Zal1);
    gat_layer<4><<<2048, 256, 0, stream>>>(x, Wsw0, Zah0, Zal0, y1);
    gat_layer<2><<<256, 256, 0, stream>>>(y1, Wsw1, Zah1, Zal1, (float*)d_out);
}